// Round 7
// baseline (445.566 us; speedup 1.0000x reference)
//
#include <hip/hip_runtime.h>
#include <stdint.h>

typedef int   i32x4 __attribute__((ext_vector_type(4)));
typedef float f32x4 __attribute__((ext_vector_type(4)));

#define AS1 __attribute__((address_space(1)))
#define AS3 __attribute__((address_space(3)))
#define G2L16(gp, lp) __builtin_amdgcn_global_load_lds((const AS1 void*)(gp), (AS3 void*)(lp), 16, 0, 0)

// ---------------- symmetric int8 row quantization (at BW floor) ----------------
template<int COLS>
__global__ __launch_bounds__(256)
void quant_rows_k(const float* __restrict__ src, int8_t* __restrict__ q,
                  float* __restrict__ scale)
{
    constexpr int PER = COLS / 256;   // 16
    static_assert(PER == 16, "pack assumes 16 elems/thread");
    const int row = blockIdx.x;
    const int t   = threadIdx.x;
    const float* s = src + (size_t)row * COLS + (size_t)t * PER;

    float v[PER];
    #pragma unroll
    for (int i = 0; i < PER; i += 4) {
        f32x4 x4 = *reinterpret_cast<const f32x4*>(s + i);
        v[i+0] = x4[0]; v[i+1] = x4[1]; v[i+2] = x4[2]; v[i+3] = x4[3];
    }
    float amax = 0.0f;
    #pragma unroll
    for (int i = 0; i < PER; ++i) amax = fmaxf(amax, fabsf(v[i]));

    #pragma unroll
    for (int off = 32; off > 0; off >>= 1)
        amax = fmaxf(amax, __shfl_xor(amax, off, 64));

    __shared__ float red[4];
    if ((t & 63) == 0) red[t >> 6] = amax;
    __syncthreads();
    amax = fmaxf(fmaxf(red[0], red[1]), fmaxf(red[2], red[3]));

    const float sc = fmaxf(amax, 1e-8f) / 127.0f;
    if (t == 0) scale[row] = sc;

    union { i32x4 v4; int8_t b[16]; } pk;
    #pragma unroll
    for (int i = 0; i < PER; ++i) {
        float r = rintf(v[i] / sc);
        r = fminf(127.0f, fmaxf(-127.0f, r));
        pk.b[i] = (int8_t)r;
    }
    *reinterpret_cast<i32x4*>(q + (size_t)row * COLS + (size_t)t * PER) = pk.v4;
}

// ---------------- int8 GEMM, 256x256 tile, 2-barrier/K-tile free-running halves ----------------
// 512 threads = 8 waves (2M x 4N), wave tile 128x64, BK = 128 B (2 k-slices of x64).
// Per K-tile, TWO half-phases, each ending in {counted vmcnt -> barrier}:
//   H1: stage s1{b0,b1}+s2{b2,b3}(next); read B@kc0/kc1 + A-mlo@kc0/kc1; 32 MFMA; vmcnt(4); BAR
//   H2: stage s3{a0,a2}+s4{a1,a3}(next); read A-mhi@kc0/kc1;             32 MFMA; vmcnt(2); BAR
// No forced lgkmcnt(0): compiler emits counted lgkm per dependent MFMA, so waves
// free-run within each half and LDS service hides under other waves' MFMA.
// Ledger (per wave, steady): enter H1 with s4(X)=2 outstanding; +s1,s2(Y)=6;
// vmcnt(4) drains s4(X). H2: +s3,s4(Y)=8; vmcnt(2) drains s1-s3(Y), keeps s4(Y).
// Every ds_read is behind {all-waves drain of its producer + barrier}.
#define BM 256
#define BN 256
#define BKB 128

__device__ __forceinline__ i32x4 mfma16(i32x4 a, i32x4 b, i32x4 c) {
    return __builtin_amdgcn_mfma_i32_16x16x64_i8(a, b, c, 0, 0, 0);
}
__device__ __forceinline__ i32x4 ldsld(const int8_t* p) {
    return *reinterpret_cast<const i32x4*>(p);
}
#define FENCE asm volatile("" ::: "memory")
#define BAR   do { FENCE; __builtin_amdgcn_s_barrier(); FENCE; } while (0)

template<bool ST>
__device__ __forceinline__ void tile_fn(
    const int8_t* __restrict__ aB, const int8_t* __restrict__ bB,  // per-thread frag bases (cur buf)
    int kc0, int kc1, i32x4 (&acc)[8][4],
    const int8_t* __restrict__ gA, const int8_t* __restrict__ gB,  // per-thread stage src (next tile)
    int8_t* lAn, int8_t* lBn,                                      // next-buf LDS bases
    size_t r64, size_t r128, int t16)
{
    // ================= H1: m 0-3, both k-slices =================
    if (ST) {                                   // stage s1={b0,b1}, s2={b2,b3}
        G2L16(gB,         lBn + t16);
        G2L16(gB + r64,   lBn + 8192  + t16);
        G2L16(gB + 2*r64, lBn + 16384 + t16);
        G2L16(gB + 3*r64, lBn + 24576 + t16);
    }
    i32x4 B00 = ldsld(bB + 0*2048 + kc0);
    i32x4 B01 = ldsld(bB + 1*2048 + kc0);
    i32x4 B02 = ldsld(bB + 2*2048 + kc0);
    i32x4 B03 = ldsld(bB + 3*2048 + kc0);
    i32x4 A00 = ldsld(aB + 0*2048 + kc0);
    i32x4 A01 = ldsld(aB + 1*2048 + kc0);
    i32x4 A02 = ldsld(aB + 2*2048 + kc0);
    i32x4 A03 = ldsld(aB + 3*2048 + kc0);
    i32x4 B10 = ldsld(bB + 0*2048 + kc1);
    i32x4 B11 = ldsld(bB + 1*2048 + kc1);
    i32x4 B12 = ldsld(bB + 2*2048 + kc1);
    i32x4 B13 = ldsld(bB + 3*2048 + kc1);
    i32x4 A20 = ldsld(aB + 0*2048 + kc1);
    i32x4 A21 = ldsld(aB + 1*2048 + kc1);
    i32x4 A22 = ldsld(aB + 2*2048 + kc1);
    i32x4 A23 = ldsld(aB + 3*2048 + kc1);
    __builtin_amdgcn_s_setprio(1);
    acc[0][0] = mfma16(A00, B00, acc[0][0]);
    acc[1][0] = mfma16(A01, B00, acc[1][0]);
    acc[2][0] = mfma16(A02, B00, acc[2][0]);
    acc[3][0] = mfma16(A03, B00, acc[3][0]);
    acc[0][1] = mfma16(A00, B01, acc[0][1]);
    acc[1][1] = mfma16(A01, B01, acc[1][1]);
    acc[2][1] = mfma16(A02, B01, acc[2][1]);
    acc[3][1] = mfma16(A03, B01, acc[3][1]);
    acc[0][2] = mfma16(A00, B02, acc[0][2]);
    acc[1][2] = mfma16(A01, B02, acc[1][2]);
    acc[2][2] = mfma16(A02, B02, acc[2][2]);
    acc[3][2] = mfma16(A03, B02, acc[3][2]);
    acc[0][3] = mfma16(A00, B03, acc[0][3]);
    acc[1][3] = mfma16(A01, B03, acc[1][3]);
    acc[2][3] = mfma16(A02, B03, acc[2][3]);
    acc[3][3] = mfma16(A03, B03, acc[3][3]);
    acc[0][0] = mfma16(A20, B10, acc[0][0]);
    acc[1][0] = mfma16(A21, B10, acc[1][0]);
    acc[2][0] = mfma16(A22, B10, acc[2][0]);
    acc[3][0] = mfma16(A23, B10, acc[3][0]);
    acc[0][1] = mfma16(A20, B11, acc[0][1]);
    acc[1][1] = mfma16(A21, B11, acc[1][1]);
    acc[2][1] = mfma16(A22, B11, acc[2][1]);
    acc[3][1] = mfma16(A23, B11, acc[3][1]);
    acc[0][2] = mfma16(A20, B12, acc[0][2]);
    acc[1][2] = mfma16(A21, B12, acc[1][2]);
    acc[2][2] = mfma16(A22, B12, acc[2][2]);
    acc[3][2] = mfma16(A23, B12, acc[3][2]);
    acc[0][3] = mfma16(A20, B13, acc[0][3]);
    acc[1][3] = mfma16(A21, B13, acc[1][3]);
    acc[2][3] = mfma16(A22, B13, acc[2][3]);
    acc[3][3] = mfma16(A23, B13, acc[3][3]);
    __builtin_amdgcn_s_setprio(0);
    // drain prev tile's s4={a1,a3} of CURRENT buf (all waves), keep s1,s2(next)
    if (ST) asm volatile("s_waitcnt vmcnt(4)" ::: "memory");
    else    asm volatile("s_waitcnt vmcnt(0)" ::: "memory");
    BAR;
    // ================= H2: m 4-7, both k-slices =================
    if (ST) {                                   // stage s3={a0,a2}, s4={a1,a3}
        G2L16(gA,              lAn + t16);
        G2L16(gA + r128,       lAn + 16384 + t16);
        G2L16(gA + r64,        lAn + 8192  + t16);
        G2L16(gA + r128 + r64, lAn + 24576 + t16);
    }
    i32x4 A10 = ldsld(aB + 4*2048 + kc0);
    i32x4 A11 = ldsld(aB + 5*2048 + kc0);
    i32x4 A12 = ldsld(aB + 6*2048 + kc0);
    i32x4 A13 = ldsld(aB + 7*2048 + kc0);
    i32x4 A30 = ldsld(aB + 4*2048 + kc1);
    i32x4 A31 = ldsld(aB + 5*2048 + kc1);
    i32x4 A32 = ldsld(aB + 6*2048 + kc1);
    i32x4 A33 = ldsld(aB + 7*2048 + kc1);
    __builtin_amdgcn_s_setprio(1);
    acc[4][0] = mfma16(A10, B00, acc[4][0]);
    acc[5][0] = mfma16(A11, B00, acc[5][0]);
    acc[6][0] = mfma16(A12, B00, acc[6][0]);
    acc[7][0] = mfma16(A13, B00, acc[7][0]);
    acc[4][1] = mfma16(A10, B01, acc[4][1]);
    acc[5][1] = mfma16(A11, B01, acc[5][1]);
    acc[6][1] = mfma16(A12, B01, acc[6][1]);
    acc[7][1] = mfma16(A13, B01, acc[7][1]);
    acc[4][2] = mfma16(A10, B02, acc[4][2]);
    acc[5][2] = mfma16(A11, B02, acc[5][2]);
    acc[6][2] = mfma16(A12, B02, acc[6][2]);
    acc[7][2] = mfma16(A13, B02, acc[7][2]);
    acc[4][3] = mfma16(A10, B03, acc[4][3]);
    acc[5][3] = mfma16(A11, B03, acc[5][3]);
    acc[6][3] = mfma16(A12, B03, acc[6][3]);
    acc[7][3] = mfma16(A13, B03, acc[7][3]);
    acc[4][0] = mfma16(A30, B10, acc[4][0]);
    acc[5][0] = mfma16(A31, B10, acc[5][0]);
    acc[6][0] = mfma16(A32, B10, acc[6][0]);
    acc[7][0] = mfma16(A33, B10, acc[7][0]);
    acc[4][1] = mfma16(A30, B11, acc[4][1]);
    acc[5][1] = mfma16(A31, B11, acc[5][1]);
    acc[6][1] = mfma16(A32, B11, acc[6][1]);
    acc[7][1] = mfma16(A33, B11, acc[7][1]);
    acc[4][2] = mfma16(A30, B12, acc[4][2]);
    acc[5][2] = mfma16(A31, B12, acc[5][2]);
    acc[6][2] = mfma16(A32, B12, acc[6][2]);
    acc[7][2] = mfma16(A33, B12, acc[7][2]);
    acc[4][3] = mfma16(A30, B13, acc[4][3]);
    acc[5][3] = mfma16(A31, B13, acc[5][3]);
    acc[6][3] = mfma16(A32, B13, acc[6][3]);
    acc[7][3] = mfma16(A33, B13, acc[7][3]);
    __builtin_amdgcn_s_setprio(0);
    if (ST) asm volatile("s_waitcnt vmcnt(2)" ::: "memory");  // drain s1-s3(next); keep s4(next)
    BAR;
}

__global__ __launch_bounds__(512, 2)
void gemm_i8_k(const int8_t* __restrict__ A,    // [M][K]
               const int8_t* __restrict__ B,    // [N][K]
               const float*  __restrict__ sx,   // [M]
               const float*  __restrict__ sw,   // [N]
               const float*  __restrict__ bias, // [N]
               float* __restrict__ C,           // [M][N]
               int M, int N, int K)
{
    __shared__ int8_t lA[2][BM * BKB];   // 2 x 32 KiB
    __shared__ int8_t lB[2][BN * BKB];   // 2 x 32 KiB

    const int t    = threadIdx.x;
    const int lane = t & 63;
    const int wid  = t >> 6;
    const int wm   = wid >> 2;   // 0..1
    const int wn   = wid & 3;    // 0..3

    const int nwg = (int)gridDim.x;
    const int bid = (int)blockIdx.x;
    const int swz = ((nwg & 7) == 0) ? ((bid & 7) * (nwg >> 3) + (bid >> 3)) : bid;
    const int nbn = N / BN;
    const int bm  = swz / nbn;
    const int bn  = swz % nbn;

    // fragment-read addressing (XOR-swizzled, matches staged source swizzle)
    const int fr  = lane & 15;
    const int c4  = lane >> 4;
    const int sw8 = fr & 7;
    const int kc0 = ((c4    ) ^ sw8) * 16;
    const int kc1 = ((c4 + 4) ^ sw8) * 16;
    const int8_t* aB0 = &lA[0][(wm * 128 + fr) * BKB];
    const int8_t* aB1 = &lA[1][(wm * 128 + fr) * BKB];
    const int8_t* bB0 = &lB[0][(wn * 64  + fr) * BKB];
    const int8_t* bB1 = &lB[1][(wn * 64  + fr) * BKB];

    // staging: thread t covers row (t>>3) of each 64-row slab, chunk ((t&7)^(row&7))
    const int srow = t >> 3;                          // 0..63
    const int skc  = ((t & 7) ^ (srow & 7)) * 16;
    const int t16  = t * 16;
    const int8_t* pA = A + (size_t)(bm * BM + srow) * K + skc;
    const int8_t* pB = B + (size_t)(bn * BN + srow) * K + skc;
    const size_t r64  = (size_t)64  * K;
    const size_t r128 = (size_t)128 * K;

    // prologue: stage K-tile 0 into buffer 0, order s1,s2,s3,s4
    G2L16(pB,              &lB[0][0]     + t16);   // b0
    G2L16(pB + r64,        &lB[0][8192]  + t16);   // b1
    G2L16(pB + 2*r64,      &lB[0][16384] + t16);   // b2
    G2L16(pB + 3*r64,      &lB[0][24576] + t16);   // b3
    G2L16(pA,              &lA[0][0]     + t16);   // a0
    G2L16(pA + r128,       &lA[0][16384] + t16);   // a2
    G2L16(pA + r64,        &lA[0][8192]  + t16);   // a1
    G2L16(pA + r128 + r64, &lA[0][24576] + t16);   // a3
    asm volatile("s_waitcnt vmcnt(2)" ::: "memory");   // s1-s3 resident; s4 in flight
    BAR;

    i32x4 acc[8][4] = {};

    const int NT = K / BKB;   // 32 (even)
    for (int tt = 0; tt + 2 < NT; tt += 2) {
        const size_t ko1 = (size_t)(tt + 1) * BKB;
        tile_fn<true>(aB0, bB0, kc0, kc1, acc, pA + ko1, pB + ko1, &lA[1][0], &lB[1][0], r64, r128, t16);
        const size_t ko2 = (size_t)(tt + 2) * BKB;
        tile_fn<true>(aB1, bB1, kc0, kc1, acc, pA + ko2, pB + ko2, &lA[0][0], &lB[0][0], r64, r128, t16);
    }
    {   // last two tiles: NT-2 (stages NT-1), then NT-1 (no stage)
        const size_t ko1 = (size_t)(NT - 1) * BKB;
        tile_fn<true >(aB0, bB0, kc0, kc1, acc, pA + ko1, pB + ko1, &lA[1][0], &lB[1][0], r64, r128, t16);
        tile_fn<false>(aB1, bB1, kc0, kc1, acc, pA, pB, &lA[0][0], &lB[0][0], r64, r128, t16);
    }

    // epilogue: dequant + bias
    const int r0 = bm * BM + wm * 128 + (c4 << 2);
    const int c0 = bn * BN + wn * 64 + fr;
    #pragma unroll
    for (int ni = 0; ni < 4; ++ni) {
        const int c = c0 + ni * 16;
        const float swc = sw[c];
        const float bc  = bias[c];
        #pragma unroll
        for (int mi = 0; mi < 8; ++mi) {
            const int rb = r0 + mi * 16;
            #pragma unroll
            for (int j = 0; j < 4; ++j) {
                const int r = rb + j;
                C[(size_t)r * N + c] = (float)acc[mi][ni][j] * sx[r] * swc + bc;
            }
        }
    }
}

extern "C" void kernel_launch(void* const* d_in, const int* in_sizes, int n_in,
                              void* d_out, int out_size, void* d_ws, size_t ws_size,
                              hipStream_t stream) {
    const float* x    = (const float*)d_in[0];
    const float* w    = (const float*)d_in[1];
    const float* bias = (const float*)d_in[2];
    float* out = (float*)d_out;

    const int dout   = in_sizes[2];          // 16384
    const int din    = in_sizes[1] / dout;   // 4096
    const int tokens = in_sizes[0] / din;    // 4096

    char* ws = (char*)d_ws;
    float*  sx = (float*)ws;
    float*  sw = (float*)(ws + 16384);
    int8_t* xq = (int8_t*)(ws + 16384 + 65536);
    int8_t* wq = xq + (size_t)tokens * din;

    quant_rows_k<4096><<<tokens, 256, 0, stream>>>(x, xq, sx);
    quant_rows_k<4096><<<dout,   256, 0, stream>>>(w, wq, sw);

    const int grid = (tokens / BM) * (dout / BN);
    gemm_i8_k<<<grid, 512, 0, stream>>>(xq, wq, sx, sw, bias, out, tokens, dout, din);
}